// Round 10
// baseline (164.641 us; speedup 1.0000x reference)
//
#include <hip/hip_runtime.h>

#define GX 432
#define GY 496
#define G_TOTAL (GX * GY) /* 214272, GZ=1 */
#define MAX_PTS 32
#define MAX_VOX 20000
#define CAP 64
#define INF_SENTINEL 0x7F7F7F7F
#define PREFIX_K 262144  /* ~133k in-range claims -> ~99k distinct cells >> 20000 */

typedef unsigned long long u64;

// IEEE float32 ops exactly matching the reference:
// c = floor((p - lo)/vs), lo = [0, -39.68, -3], vs = [.16,.16,4].
__device__ __forceinline__ int cell_of(float4 p, bool& ok) {
    float fx = floorf((p.x - 0.0f) / 0.16f);
    float fy = floorf((p.y + 39.68f) / 0.16f);
    float fz = floorf((p.z + 3.0f) / 4.0f);
    int cx = (int)fx, cy = (int)fy, cz = (int)fz;
    ok = (cx >= 0 && cx < GX && cy >= 0 && cy < GY && cz == 0);
    return cy * GX + cx;
}

// Pass 1: 1 point/thread (coalesced — R9's 2pt/thread strided form regressed).
// Fused inits + lin[] store for ALL points + cell claim (atomicMin) only for
// the prefix i < K. dcount (distinct cells claimed) from atomicMin return:
// old==INF happens exactly once per cell. dcount starts at INF_SENTINEL.
__global__ __launch_bounds__(256) void pass1(const float4* __restrict__ pts,
                                             int* __restrict__ lin,
                                             int* __restrict__ first,
                                             u64* __restrict__ bits,
                                             int* __restrict__ vcount,
                                             int* __restrict__ cellOfRank,
                                             int* __restrict__ rank,
                                             int* __restrict__ dcount,
                                             int W, int K, int n) {
    int i = blockIdx.x * 256 + threadIdx.x;
    // fused inits (consumed only by LATER kernels)
    if (i < W) bits[i] = 0ull;
    if (i < MAX_VOX) { vcount[i] = -1; cellOfRank[i] = -1; }
    if (i < G_TOTAL) rank[i] = INF_SENTINEL;  // cells never ranked -> huge
    int claims = 0;
    if (i < n) {
        float4 p = pts[i];
        bool ok;
        int c = cell_of(p, ok);
        lin[i] = ok ? c : -1;
        if (ok && i < K)
            claims = (atomicMin(&first[c], i) == INF_SENTINEL);
    }
    // wave-aggregate distinct-claim count
    for (int d = 32; d >= 1; d >>= 1) claims += __shfl_down(claims, d, 64);
    if ((threadIdx.x & 63) == 0 && claims > 0) atomicAdd(dcount, claims);
}

// Guard: if the prefix produced fewer than MAX_VOX distinct cells, the prefix
// bound is insufficient — claim the remaining points too (filtered atomicMin;
// predicate proven exact in round 7). No-op for this input distribution.
__global__ __launch_bounds__(256) void guard(const float4* __restrict__ pts,
                                             int* __restrict__ first,
                                             const int* __restrict__ dcount,
                                             int K, int n) {
    if (*(volatile int*)dcount - INF_SENTINEL >= MAX_VOX) return;
    for (int i = K + blockIdx.x * 256 + threadIdx.x; i < n;
         i += gridDim.x * 256) {
        float4 p = pts[i];
        bool ok;
        int c = cell_of(p, ok);
        if (ok && first[c] > i) atomicMin(&first[c], i);
    }
}

// Mark first-point bits directly: distinct cells have distinct first indices;
// atomicOr handles same-word collisions. bits[] is L2-resident (250 KB).
__global__ __launch_bounds__(256) void markFirst(const int* __restrict__ first,
                                                 u64* __restrict__ bits, int n) {
    int c = blockIdx.x * 256 + threadIdx.x;
    if (c >= G_TOTAL) return;
    int f = first[c];
    if (f >= 0 && f < n) atomicOr(&bits[f >> 6], 1ull << (f & 63));
}

// Fused scan (last-block pattern): popcount bits[], per-word intra-block
// exclusive prefix (wordLocal) + per-block sums; the LAST block to finish
// exclusive-scans the block sums in place and writes num_voxels.
// ticket starts at INF_SENTINEL (0x7F memset).
__global__ __launch_bounds__(256) void kScan(const u64* __restrict__ bits,
                                             unsigned* __restrict__ wordLocal,
                                             int* __restrict__ sums,
                                             int* __restrict__ ticket,
                                             float* __restrict__ nvOut, int W,
                                             int nbW) {
    __shared__ int wsum[4], wexc[4];
    __shared__ int lastFlag;
    int t = threadIdx.x;
    int wi = blockIdx.x * 256 + t;
    u64 mask = (wi < W) ? bits[wi] : 0ull;
    int v = __popcll(mask);
    int lane = t & 63, w = t >> 6;
    int x = v;
    for (int d = 1; d < 64; d <<= 1) {
        int y = __shfl_up(x, d, 64);
        if (lane >= d) x += y;
    }
    if (lane == 63) wsum[w] = x;
    __syncthreads();
    if (t == 0) {
        int a = 0;
        for (int j = 0; j < 4; j++) { wexc[j] = a; a += wsum[j]; }
        sums[blockIdx.x] = a;
        __threadfence();
        int old = atomicAdd(ticket, 1);
        lastFlag = (old - INF_SENTINEL == nbW - 1);
    }
    __syncthreads();
    if (wi < W) wordLocal[wi] = (unsigned)(wexc[w] + x - v);
    if (!lastFlag) return;
    // ---- last block: exclusive-scan sums[0..nbW) (nbW <= 128) ----
    int sv = 0;
    if (t < nbW)
        sv = __hip_atomic_load(&sums[t], __ATOMIC_RELAXED,
                               __HIP_MEMORY_SCOPE_AGENT);
    int sx = sv;
    for (int d = 1; d < 64; d <<= 1) {
        int y = __shfl_up(sx, d, 64);
        if (lane >= d) sx += y;
    }
    __syncthreads();  // reuse wsum safely
    if (lane == 63) wsum[w] = sx;
    __syncthreads();
    if (t == 0) {
        int a = 0;
        for (int j = 0; j < 2; j++) { wexc[j] = a; a += wsum[j]; }
        nvOut[0] = (float)(a < MAX_VOX ? a : MAX_VOX);
    }
    __syncthreads();
    if (t < nbW) sums[t] = wexc[w] + sx - sv;
}

// Rank cells: O(1) per cell — block base + intra-block word prefix + bit pop.
__global__ __launch_bounds__(256) void rankCells(const int* __restrict__ first,
                                                 const u64* __restrict__ bits,
                                                 const unsigned* __restrict__ wordLocal,
                                                 const int* __restrict__ sumsExcl,
                                                 int* __restrict__ rank,
                                                 int* __restrict__ cellOfRank, int n) {
    int c = blockIdx.x * 256 + threadIdx.x;
    if (c >= G_TOTAL) return;
    int f = first[c];
    if (f < 0 || f >= n) return;
    int wf = f >> 6;
    int b = f & 63;
    u64 lowmask = (b == 0) ? 0ull : ((~0ull) >> (64 - b));
    int vr = sumsExcl[wf >> 8] + (int)wordLocal[wf] + __popcll(bits[wf] & lowmask);
    rank[c] = vr;
    if (vr < MAX_VOX) cellOfRank[vr] = c;
}

// Pass 5: 1 point/thread (R9's 4pt/thread form cut TLP on a latency-bound
// kernel). Append point indices into kept voxels' lists. vcount starts at -1;
// atomicAdd returns old, pos = old+1. rank[] is INF for never-ranked cells.
__global__ __launch_bounds__(256) void pass5(const int* __restrict__ lin,
                                             const int* __restrict__ rank,
                                             int* __restrict__ vcount,
                                             int* __restrict__ list, int n) {
    int i = blockIdx.x * 256 + threadIdx.x;
    if (i >= n) return;
    int c = lin[i];
    if (c < 0) return;
    int vr = rank[c];
    if (vr >= MAX_VOX) return;
    int pos = atomicAdd(&vcount[vr], 1) + 1;
    if (pos < CAP) list[vr * CAP + pos] = i;
}

// Pass F: 4 voxels per 256-thread block (one wave each). Counting-sort the
// collected indices (LDS broadcast reads), write all 32 slots + num_points
// + coors (so no d_out pre-memset is needed).
__global__ __launch_bounds__(256) void passF(const float4* __restrict__ pts,
                                             const int* __restrict__ vcount,
                                             const int* __restrict__ cellOfRank,
                                             const int* __restrict__ list,
                                             float4* __restrict__ voxOut,
                                             float* __restrict__ coorsOut,
                                             float* __restrict__ npOut) {
    __shared__ int s[4][CAP];
    __shared__ int slotPt[4][MAX_PTS];
    int w = threadIdx.x >> 6, lane = threadIdx.x & 63;
    int v = blockIdx.x * 4 + w;
    int cnt = vcount[v] + 1;
    int m = cnt < CAP ? cnt : CAP;
    s[w][lane] = (lane < m) ? list[v * CAP + lane] : 0x7FFFFFFF;
    if (lane < MAX_PTS) slotPt[w][lane] = -1;
    __syncthreads();
    int my = s[w][lane];
    int r = 0;
#pragma unroll
    for (int j = 0; j < CAP; j++) r += (s[w][j] < my) ? 1 : 0;  // broadcast
    if (lane < m && r < MAX_PTS) slotPt[w][r] = my;
    __syncthreads();
    if (lane < MAX_PTS) {
        int p = slotPt[w][lane];
        float4 val = make_float4(0.f, 0.f, 0.f, 0.f);
        if (p >= 0) val = pts[p];
        voxOut[(size_t)v * MAX_PTS + lane] = val;
    }
    if (lane == 0) {
        npOut[v] = (float)(cnt < MAX_PTS ? cnt : MAX_PTS);
        int cell = cellOfRank[v];
        if (cell < 0) {
            coorsOut[3 * v + 0] = -1.0f;
            coorsOut[3 * v + 1] = -1.0f;
            coorsOut[3 * v + 2] = -1.0f;
        } else {
            coorsOut[3 * v + 0] = 0.0f;  // cz (GZ==1)
            coorsOut[3 * v + 1] = (float)(cell / GX);
            coorsOut[3 * v + 2] = (float)(cell % GX);
        }
    }
}

extern "C" void kernel_launch(void* const* d_in, const int* in_sizes, int n_in,
                              void* d_out, int out_size, void* d_ws, size_t ws_size,
                              hipStream_t stream) {
    const float4* pts = (const float4*)d_in[0];
    int n = in_sizes[0] / 4;  // 2,000,000
    int W = (n + 63) >> 6;    // 31250 bitmap words
    int K = PREFIX_K < n ? PREFIX_K : n;

    char* ws = (char*)d_ws;
    size_t off = 0;
    auto alloc = [&](size_t bytes) -> void* {
        void* p = (void*)(ws + off);
        off = (off + bytes + 255) & ~(size_t)255;
        return p;
    };
    int* first = (int*)alloc((size_t)(G_TOTAL + 8) * 4);  // + dcount + ticket
    int* dcount = first + G_TOTAL;
    int* ticket = first + G_TOTAL + 1;
    int* lin = (int*)alloc((size_t)n * 4);
    u64* bits = (u64*)alloc((size_t)W * 8);
    unsigned* wordLocal = (unsigned*)alloc((size_t)W * 4);
    int* sums = (int*)alloc(128 * 4);
    int* rank = (int*)alloc((size_t)G_TOTAL * 4);
    int* vcount = (int*)alloc((size_t)MAX_VOX * 4);
    int* cellOfRank = (int*)alloc((size_t)MAX_VOX * 4);
    int* list = (int*)alloc((size_t)MAX_VOX * CAP * 4);
    (void)ws_size;
    (void)n_in;
    (void)out_size;

    float* out = (float*)d_out;
    float4* voxOut = (float4*)out;                          // 20000*32*4
    float* coorsOut = out + (size_t)MAX_VOX * MAX_PTS * 4;  // 20000*3
    float* npOut = coorsOut + (size_t)MAX_VOX * 3;          // 20000
    float* nvOut = npOut + MAX_VOX;                         // 1

    // first/dcount/ticket all -> 0x7F7F7F7F
    hipMemsetAsync(first, 0x7F, (size_t)(G_TOTAL + 8) * 4, stream);

    int nbP = (n + 255) / 256;        // 7813
    int nbC = (G_TOTAL + 255) / 256;  // 837
    int nbW = (W + 255) / 256;        // 123

    pass1<<<nbP, 256, 0, stream>>>(pts, lin, first, bits, vcount, cellOfRank,
                                   rank, dcount, W, K, n);
    guard<<<256, 256, 0, stream>>>(pts, first, dcount, K, n);
    markFirst<<<nbC, 256, 0, stream>>>(first, bits, n);
    kScan<<<nbW, 256, 0, stream>>>(bits, wordLocal, sums, ticket, nvOut, W, nbW);
    rankCells<<<nbC, 256, 0, stream>>>(first, bits, wordLocal, sums, rank,
                                       cellOfRank, n);
    pass5<<<nbP, 256, 0, stream>>>(lin, rank, vcount, list, n);
    passF<<<MAX_VOX / 4, 256, 0, stream>>>(pts, vcount, cellOfRank, list,
                                           voxOut, coorsOut, npOut);
}

// Round 11
// 133.328 us; speedup vs baseline: 1.2349x; 1.2349x over previous
//
#include <hip/hip_runtime.h>

#define GX 432
#define GY 496
#define G_TOTAL (GX * GY) /* 214272, GZ=1 */
#define MAX_PTS 32
#define MAX_VOX 20000
#define CAP 64
#define INF_SENTINEL 0x7F7F7F7F
#define PREFIX_K 262144  /* ~133k in-range claims -> ~99k distinct cells >> 20000 */

typedef unsigned long long u64;

// IEEE float32 ops exactly matching the reference:
// c = floor((p - lo)/vs), lo = [0, -39.68, -3], vs = [.16,.16,4].
__device__ __forceinline__ int cell_of(float4 p, bool& ok) {
    float fx = floorf((p.x - 0.0f) / 0.16f);
    float fy = floorf((p.y + 39.68f) / 0.16f);
    float fz = floorf((p.z + 3.0f) / 4.0f);
    int cx = (int)fx, cy = (int)fy, cz = (int)fz;
    ok = (cx >= 0 && cx < GX && cy >= 0 && cy < GY && cz == 0);
    return cy * GX + cx;
}

// Pass 1: 1 point/thread, NON-RETURNING atomicMin (using the return value
// forces a per-wave vmcnt drain on a ~900cy round-trip — R9/R10 regression).
// Fused inits + lin[] store for ALL points + cell claim only for i < K.
__global__ __launch_bounds__(256) void pass1(const float4* __restrict__ pts,
                                             int* __restrict__ lin,
                                             int* __restrict__ first,
                                             u64* __restrict__ bits,
                                             int* __restrict__ vcount,
                                             int* __restrict__ cellOfRank,
                                             int* __restrict__ rank,
                                             int* __restrict__ dcount,
                                             int W, int K, int n) {
    int i = blockIdx.x * 256 + threadIdx.x;
    // fused inits (consumed only by LATER kernels)
    if (i < W) bits[i] = 0ull;
    if (i < MAX_VOX) { vcount[i] = -1; cellOfRank[i] = -1; }
    if (i < G_TOTAL) rank[i] = INF_SENTINEL;  // cells never ranked -> huge
    if (i == 0) *dcount = 0;
    if (i >= n) return;
    float4 p = pts[i];
    bool ok;
    int c = cell_of(p, ok);
    lin[i] = ok ? c : -1;
    if (ok && i < K) atomicMin(&first[c], i);  // return value UNUSED: fire-and-forget
}

// Count distinct cells claimed by the prefix (L2-resident 857KB scan, ~1.5us).
// Separate kernel so pass1's atomics stay non-returning.
__global__ __launch_bounds__(256) void countD(const int* __restrict__ first,
                                              int* __restrict__ dcount) {
    __shared__ int wsh[4];
    int c = blockIdx.x * 256 + threadIdx.x;
    int have = (c < G_TOTAL && first[c] != INF_SENTINEL) ? 1 : 0;
    for (int d = 32; d >= 1; d >>= 1) have += __shfl_down(have, d, 64);
    if ((threadIdx.x & 63) == 0) wsh[threadIdx.x >> 6] = have;
    __syncthreads();
    if (threadIdx.x == 0)
        atomicAdd(dcount, wsh[0] + wsh[1] + wsh[2] + wsh[3]);
}

// Guard: if the prefix produced fewer than MAX_VOX distinct cells, the prefix
// bound is insufficient — claim the remaining points too (filtered atomicMin;
// predicate proven exact in round 7). No-op for this input distribution.
__global__ __launch_bounds__(256) void guard(const float4* __restrict__ pts,
                                             int* __restrict__ first,
                                             const int* __restrict__ dcount,
                                             int K, int n) {
    if (*(volatile int*)dcount >= MAX_VOX) return;
    for (int i = K + blockIdx.x * 256 + threadIdx.x; i < n;
         i += gridDim.x * 256) {
        float4 p = pts[i];
        bool ok;
        int c = cell_of(p, ok);
        if (ok && first[c] > i) atomicMin(&first[c], i);
    }
}

// Mark first-point bits directly: distinct cells have distinct first indices;
// atomicOr handles same-word collisions. bits[] is L2-resident (250 KB).
// Return value unused -> fire-and-forget.
__global__ __launch_bounds__(256) void markFirst(const int* __restrict__ first,
                                                 u64* __restrict__ bits, int n) {
    int c = blockIdx.x * 256 + threadIdx.x;
    if (c >= G_TOTAL) return;
    int f = first[c];
    if (f >= 0 && f < n) atomicOr(&bits[f >> 6], 1ull << (f & 63));
}

// Fused scan (last-block pattern): popcount bits[], per-word intra-block
// exclusive prefix (wordLocal) + per-block sums; the LAST block to finish
// exclusive-scans the block sums in place and writes num_voxels.
// ticket starts at INF_SENTINEL (0x7F memset).
__global__ __launch_bounds__(256) void kScan(const u64* __restrict__ bits,
                                             unsigned* __restrict__ wordLocal,
                                             int* __restrict__ sums,
                                             int* __restrict__ ticket,
                                             float* __restrict__ nvOut, int W,
                                             int nbW) {
    __shared__ int wsum[4], wexc[4];
    __shared__ int lastFlag;
    int t = threadIdx.x;
    int wi = blockIdx.x * 256 + t;
    u64 mask = (wi < W) ? bits[wi] : 0ull;
    int v = __popcll(mask);
    int lane = t & 63, w = t >> 6;
    int x = v;
    for (int d = 1; d < 64; d <<= 1) {
        int y = __shfl_up(x, d, 64);
        if (lane >= d) x += y;
    }
    if (lane == 63) wsum[w] = x;
    __syncthreads();
    if (t == 0) {
        int a = 0;
        for (int j = 0; j < 4; j++) { wexc[j] = a; a += wsum[j]; }
        sums[blockIdx.x] = a;
        __threadfence();
        int old = atomicAdd(ticket, 1);
        lastFlag = (old - INF_SENTINEL == nbW - 1);
    }
    __syncthreads();
    if (wi < W) wordLocal[wi] = (unsigned)(wexc[w] + x - v);
    if (!lastFlag) return;
    // ---- last block: exclusive-scan sums[0..nbW) (nbW <= 128) ----
    int sv = 0;
    if (t < nbW)
        sv = __hip_atomic_load(&sums[t], __ATOMIC_RELAXED,
                               __HIP_MEMORY_SCOPE_AGENT);
    int sx = sv;
    for (int d = 1; d < 64; d <<= 1) {
        int y = __shfl_up(sx, d, 64);
        if (lane >= d) sx += y;
    }
    __syncthreads();  // reuse wsum safely
    if (lane == 63) wsum[w] = sx;
    __syncthreads();
    if (t == 0) {
        int a = 0;
        for (int j = 0; j < 2; j++) { wexc[j] = a; a += wsum[j]; }
        nvOut[0] = (float)(a < MAX_VOX ? a : MAX_VOX);
    }
    __syncthreads();
    if (t < nbW) sums[t] = wexc[w] + sx - sv;
}

// Rank cells: O(1) per cell — block base + intra-block word prefix + bit pop.
__global__ __launch_bounds__(256) void rankCells(const int* __restrict__ first,
                                                 const u64* __restrict__ bits,
                                                 const unsigned* __restrict__ wordLocal,
                                                 const int* __restrict__ sumsExcl,
                                                 int* __restrict__ rank,
                                                 int* __restrict__ cellOfRank, int n) {
    int c = blockIdx.x * 256 + threadIdx.x;
    if (c >= G_TOTAL) return;
    int f = first[c];
    if (f < 0 || f >= n) return;
    int wf = f >> 6;
    int b = f & 63;
    u64 lowmask = (b == 0) ? 0ull : ((~0ull) >> (64 - b));
    int vr = sumsExcl[wf >> 8] + (int)wordLocal[wf] + __popcll(bits[wf] & lowmask);
    rank[c] = vr;
    if (vr < MAX_VOX) cellOfRank[vr] = c;
}

// Pass 5: 1 point/thread. Append point indices into kept voxels' lists.
// vcount starts at -1; atomicAdd returns old, pos = old+1 (return needed
// here — it IS the slot ticket). rank[] is INF for never-ranked cells,
// filtering ~91% of in-range points before any atomic.
__global__ __launch_bounds__(256) void pass5(const int* __restrict__ lin,
                                             const int* __restrict__ rank,
                                             int* __restrict__ vcount,
                                             int* __restrict__ list, int n) {
    int i = blockIdx.x * 256 + threadIdx.x;
    if (i >= n) return;
    int c = lin[i];
    if (c < 0) return;
    int vr = rank[c];
    if (vr >= MAX_VOX) return;
    int pos = atomicAdd(&vcount[vr], 1) + 1;
    if (pos < CAP) list[vr * CAP + pos] = i;
}

// Pass F: 4 voxels per 256-thread block (one wave each). Counting-sort the
// collected indices (LDS broadcast reads), write all 32 slots + num_points
// + coors (so no d_out pre-memset is needed).
__global__ __launch_bounds__(256) void passF(const float4* __restrict__ pts,
                                             const int* __restrict__ vcount,
                                             const int* __restrict__ cellOfRank,
                                             const int* __restrict__ list,
                                             float4* __restrict__ voxOut,
                                             float* __restrict__ coorsOut,
                                             float* __restrict__ npOut) {
    __shared__ int s[4][CAP];
    __shared__ int slotPt[4][MAX_PTS];
    int w = threadIdx.x >> 6, lane = threadIdx.x & 63;
    int v = blockIdx.x * 4 + w;
    int cnt = vcount[v] + 1;
    int m = cnt < CAP ? cnt : CAP;
    s[w][lane] = (lane < m) ? list[v * CAP + lane] : 0x7FFFFFFF;
    if (lane < MAX_PTS) slotPt[w][lane] = -1;
    __syncthreads();
    int my = s[w][lane];
    int r = 0;
#pragma unroll
    for (int j = 0; j < CAP; j++) r += (s[w][j] < my) ? 1 : 0;  // broadcast
    if (lane < m && r < MAX_PTS) slotPt[w][r] = my;
    __syncthreads();
    if (lane < MAX_PTS) {
        int p = slotPt[w][lane];
        float4 val = make_float4(0.f, 0.f, 0.f, 0.f);
        if (p >= 0) val = pts[p];
        voxOut[(size_t)v * MAX_PTS + lane] = val;
    }
    if (lane == 0) {
        npOut[v] = (float)(cnt < MAX_PTS ? cnt : MAX_PTS);
        int cell = cellOfRank[v];
        if (cell < 0) {
            coorsOut[3 * v + 0] = -1.0f;
            coorsOut[3 * v + 1] = -1.0f;
            coorsOut[3 * v + 2] = -1.0f;
        } else {
            coorsOut[3 * v + 0] = 0.0f;  // cz (GZ==1)
            coorsOut[3 * v + 1] = (float)(cell / GX);
            coorsOut[3 * v + 2] = (float)(cell % GX);
        }
    }
}

extern "C" void kernel_launch(void* const* d_in, const int* in_sizes, int n_in,
                              void* d_out, int out_size, void* d_ws, size_t ws_size,
                              hipStream_t stream) {
    const float4* pts = (const float4*)d_in[0];
    int n = in_sizes[0] / 4;  // 2,000,000
    int W = (n + 63) >> 6;    // 31250 bitmap words
    int K = PREFIX_K < n ? PREFIX_K : n;

    char* ws = (char*)d_ws;
    size_t off = 0;
    auto alloc = [&](size_t bytes) -> void* {
        void* p = (void*)(ws + off);
        off = (off + bytes + 255) & ~(size_t)255;
        return p;
    };
    int* first = (int*)alloc((size_t)(G_TOTAL + 8) * 4);  // + dcount + ticket
    int* dcount = first + G_TOTAL;
    int* ticket = first + G_TOTAL + 1;
    int* lin = (int*)alloc((size_t)n * 4);
    u64* bits = (u64*)alloc((size_t)W * 8);
    unsigned* wordLocal = (unsigned*)alloc((size_t)W * 4);
    int* sums = (int*)alloc(128 * 4);
    int* rank = (int*)alloc((size_t)G_TOTAL * 4);
    int* vcount = (int*)alloc((size_t)MAX_VOX * 4);
    int* cellOfRank = (int*)alloc((size_t)MAX_VOX * 4);
    int* list = (int*)alloc((size_t)MAX_VOX * CAP * 4);
    (void)ws_size;
    (void)n_in;
    (void)out_size;

    float* out = (float*)d_out;
    float4* voxOut = (float4*)out;                          // 20000*32*4
    float* coorsOut = out + (size_t)MAX_VOX * MAX_PTS * 4;  // 20000*3
    float* npOut = coorsOut + (size_t)MAX_VOX * 3;          // 20000
    float* nvOut = npOut + MAX_VOX;                         // 1

    // first/dcount/ticket all -> 0x7F7F7F7F (dcount re-zeroed in pass1)
    hipMemsetAsync(first, 0x7F, (size_t)(G_TOTAL + 8) * 4, stream);

    int nbP = (n + 255) / 256;        // 7813
    int nbC = (G_TOTAL + 255) / 256;  // 837
    int nbW = (W + 255) / 256;        // 123

    pass1<<<nbP, 256, 0, stream>>>(pts, lin, first, bits, vcount, cellOfRank,
                                   rank, dcount, W, K, n);
    countD<<<nbC, 256, 0, stream>>>(first, dcount);
    guard<<<256, 256, 0, stream>>>(pts, first, dcount, K, n);
    markFirst<<<nbC, 256, 0, stream>>>(first, bits, n);
    kScan<<<nbW, 256, 0, stream>>>(bits, wordLocal, sums, ticket, nvOut, W, nbW);
    rankCells<<<nbC, 256, 0, stream>>>(first, bits, wordLocal, sums, rank,
                                       cellOfRank, n);
    pass5<<<nbP, 256, 0, stream>>>(lin, rank, vcount, list, n);
    passF<<<MAX_VOX / 4, 256, 0, stream>>>(pts, vcount, cellOfRank, list,
                                           voxOut, coorsOut, npOut);
}

// Round 12
// 128.520 us; speedup vs baseline: 1.2811x; 1.0374x over previous
//
#include <hip/hip_runtime.h>

#define GX 432
#define GY 496
#define G_TOTAL (GX * GY) /* 214272, GZ=1 */
#define MAX_PTS 32
#define MAX_VOX 20000
#define CAP 64
#define INF_SENTINEL 0x7F7F7F7F
#define PREFIX_K 65536  /* ~33k in-range claims -> ~31k distinct cells >= 20000 */

typedef unsigned long long u64;

// IEEE float32 ops exactly matching the reference:
// c = floor((p - lo)/vs), lo = [0, -39.68, -3], vs = [.16,.16,4].
__device__ __forceinline__ int cell_of(float4 p, bool& ok) {
    float fx = floorf((p.x - 0.0f) / 0.16f);
    float fy = floorf((p.y + 39.68f) / 0.16f);
    float fz = floorf((p.z + 3.0f) / 4.0f);
    int cx = (int)fx, cy = (int)fy, cz = (int)fz;
    ok = (cx >= 0 && cx < GX && cy >= 0 && cy < GY && cz == 0);
    return cy * GX + cx;
}

// Claim kernel: ONLY the K-point prefix does scattered atomics (non-returning
// — using the return value costs a per-wave ~900cy drain, R10 regression).
// Kept separate from the streaming pass so the 40MB stream isn't dragged to
// the scattered-atomic pace (R1/R5: ~23G scattered atomics/s ceiling).
__global__ __launch_bounds__(256) void claimK(const float4* __restrict__ pts,
                                              int* __restrict__ first,
                                              int* __restrict__ dcount, int K) {
    int i = blockIdx.x * 256 + threadIdx.x;
    if (i == 0) *dcount = 0;
    if (i >= K) return;
    float4 p = pts[i];
    bool ok;
    int c = cell_of(p, ok);
    if (ok) atomicMin(&first[c], i);  // return value UNUSED: fire-and-forget
}

// Streaming kernel: pure BW — reads all points, writes lin[], fused inits.
// ZERO atomics, zero scattered traffic.
__global__ __launch_bounds__(256) void linAll(const float4* __restrict__ pts,
                                              int* __restrict__ lin,
                                              u64* __restrict__ bits,
                                              int* __restrict__ vcount,
                                              int* __restrict__ cellOfRank,
                                              int* __restrict__ rank,
                                              int W, int n) {
    int i = blockIdx.x * 256 + threadIdx.x;
    // fused inits (consumed only by LATER kernels)
    if (i < W) bits[i] = 0ull;
    if (i < MAX_VOX) { vcount[i] = -1; cellOfRank[i] = -1; }
    if (i < G_TOTAL) rank[i] = INF_SENTINEL;  // cells never ranked -> huge
    if (i >= n) return;
    float4 p = pts[i];
    bool ok;
    int c = cell_of(p, ok);
    lin[i] = ok ? c : -1;
}

// Count distinct cells claimed by the prefix (L2-resident 857KB scan).
__global__ __launch_bounds__(256) void countD(const int* __restrict__ first,
                                              int* __restrict__ dcount) {
    __shared__ int wsh[4];
    int c = blockIdx.x * 256 + threadIdx.x;
    int have = (c < G_TOTAL && first[c] != INF_SENTINEL) ? 1 : 0;
    for (int d = 32; d >= 1; d >>= 1) have += __shfl_down(have, d, 64);
    if ((threadIdx.x & 63) == 0) wsh[threadIdx.x >> 6] = have;
    __syncthreads();
    if (threadIdx.x == 0)
        atomicAdd(dcount, wsh[0] + wsh[1] + wsh[2] + wsh[3]);
}

// Guard: if the prefix produced fewer than MAX_VOX distinct cells, the prefix
// bound is insufficient — claim the remaining points too (filtered atomicMin;
// predicate proven exact in round 7). No-op for this input distribution.
__global__ __launch_bounds__(256) void guard(const float4* __restrict__ pts,
                                             int* __restrict__ first,
                                             const int* __restrict__ dcount,
                                             int K, int n) {
    if (*(volatile int*)dcount >= MAX_VOX) return;
    for (int i = K + blockIdx.x * 256 + threadIdx.x; i < n;
         i += gridDim.x * 256) {
        float4 p = pts[i];
        bool ok;
        int c = cell_of(p, ok);
        if (ok && first[c] > i) atomicMin(&first[c], i);
    }
}

// Mark first-point bits directly: distinct cells have distinct first indices;
// atomicOr handles same-word collisions. bits[] is L2-resident; fire-and-forget.
__global__ __launch_bounds__(256) void markFirst(const int* __restrict__ first,
                                                 u64* __restrict__ bits, int n) {
    int c = blockIdx.x * 256 + threadIdx.x;
    if (c >= G_TOTAL) return;
    int f = first[c];
    if (f >= 0 && f < n) atomicOr(&bits[f >> 6], 1ull << (f & 63));
}

// Fused scan (last-block pattern): popcount bits[], per-word intra-block
// exclusive prefix (wordLocal) + per-block sums; the LAST block to finish
// exclusive-scans the block sums in place and writes num_voxels.
// ticket starts at INF_SENTINEL (0x7F memset).
__global__ __launch_bounds__(256) void kScan(const u64* __restrict__ bits,
                                             unsigned* __restrict__ wordLocal,
                                             int* __restrict__ sums,
                                             int* __restrict__ ticket,
                                             float* __restrict__ nvOut, int W,
                                             int nbW) {
    __shared__ int wsum[4], wexc[4];
    __shared__ int lastFlag;
    int t = threadIdx.x;
    int wi = blockIdx.x * 256 + t;
    u64 mask = (wi < W) ? bits[wi] : 0ull;
    int v = __popcll(mask);
    int lane = t & 63, w = t >> 6;
    int x = v;
    for (int d = 1; d < 64; d <<= 1) {
        int y = __shfl_up(x, d, 64);
        if (lane >= d) x += y;
    }
    if (lane == 63) wsum[w] = x;
    __syncthreads();
    if (t == 0) {
        int a = 0;
        for (int j = 0; j < 4; j++) { wexc[j] = a; a += wsum[j]; }
        sums[blockIdx.x] = a;
        __threadfence();
        int old = atomicAdd(ticket, 1);
        lastFlag = (old - INF_SENTINEL == nbW - 1);
    }
    __syncthreads();
    if (wi < W) wordLocal[wi] = (unsigned)(wexc[w] + x - v);
    if (!lastFlag) return;
    // ---- last block: exclusive-scan sums[0..nbW) (nbW <= 128) ----
    int sv = 0;
    if (t < nbW)
        sv = __hip_atomic_load(&sums[t], __ATOMIC_RELAXED,
                               __HIP_MEMORY_SCOPE_AGENT);
    int sx = sv;
    for (int d = 1; d < 64; d <<= 1) {
        int y = __shfl_up(sx, d, 64);
        if (lane >= d) sx += y;
    }
    __syncthreads();  // reuse wsum safely
    if (lane == 63) wsum[w] = sx;
    __syncthreads();
    if (t == 0) {
        int a = 0;
        for (int j = 0; j < 2; j++) { wexc[j] = a; a += wsum[j]; }
        nvOut[0] = (float)(a < MAX_VOX ? a : MAX_VOX);
    }
    __syncthreads();
    if (t < nbW) sums[t] = wexc[w] + sx - sv;
}

// Rank cells: O(1) per cell — block base + intra-block word prefix + bit pop.
__global__ __launch_bounds__(256) void rankCells(const int* __restrict__ first,
                                                 const u64* __restrict__ bits,
                                                 const unsigned* __restrict__ wordLocal,
                                                 const int* __restrict__ sumsExcl,
                                                 int* __restrict__ rank,
                                                 int* __restrict__ cellOfRank, int n) {
    int c = blockIdx.x * 256 + threadIdx.x;
    if (c >= G_TOTAL) return;
    int f = first[c];
    if (f < 0 || f >= n) return;
    int wf = f >> 6;
    int b = f & 63;
    u64 lowmask = (b == 0) ? 0ull : ((~0ull) >> (64 - b));
    int vr = sumsExcl[wf >> 8] + (int)wordLocal[wf] + __popcll(bits[wf] & lowmask);
    rank[c] = vr;
    if (vr < MAX_VOX) cellOfRank[vr] = c;
}

// Pass 5: 1 point/thread. Append point indices into kept voxels' lists.
// vcount starts at -1; atomicAdd returns old, pos = old+1 (return needed
// here — it IS the slot ticket, and only ~95k of 2M points reach it).
__global__ __launch_bounds__(256) void pass5(const int* __restrict__ lin,
                                             const int* __restrict__ rank,
                                             int* __restrict__ vcount,
                                             int* __restrict__ list, int n) {
    int i = blockIdx.x * 256 + threadIdx.x;
    if (i >= n) return;
    int c = lin[i];
    if (c < 0) return;
    int vr = rank[c];
    if (vr >= MAX_VOX) return;
    int pos = atomicAdd(&vcount[vr], 1) + 1;
    if (pos < CAP) list[vr * CAP + pos] = i;
}

// Pass F: 4 voxels per 256-thread block (one wave each). Counting-sort the
// collected indices (LDS broadcast reads), write all 32 slots + num_points
// + coors (so no d_out pre-memset is needed).
__global__ __launch_bounds__(256) void passF(const float4* __restrict__ pts,
                                             const int* __restrict__ vcount,
                                             const int* __restrict__ cellOfRank,
                                             const int* __restrict__ list,
                                             float4* __restrict__ voxOut,
                                             float* __restrict__ coorsOut,
                                             float* __restrict__ npOut) {
    __shared__ int s[4][CAP];
    __shared__ int slotPt[4][MAX_PTS];
    int w = threadIdx.x >> 6, lane = threadIdx.x & 63;
    int v = blockIdx.x * 4 + w;
    int cnt = vcount[v] + 1;
    int m = cnt < CAP ? cnt : CAP;
    s[w][lane] = (lane < m) ? list[v * CAP + lane] : 0x7FFFFFFF;
    if (lane < MAX_PTS) slotPt[w][lane] = -1;
    __syncthreads();
    int my = s[w][lane];
    int r = 0;
#pragma unroll
    for (int j = 0; j < CAP; j++) r += (s[w][j] < my) ? 1 : 0;  // broadcast
    if (lane < m && r < MAX_PTS) slotPt[w][r] = my;
    __syncthreads();
    if (lane < MAX_PTS) {
        int p = slotPt[w][lane];
        float4 val = make_float4(0.f, 0.f, 0.f, 0.f);
        if (p >= 0) val = pts[p];
        voxOut[(size_t)v * MAX_PTS + lane] = val;
    }
    if (lane == 0) {
        npOut[v] = (float)(cnt < MAX_PTS ? cnt : MAX_PTS);
        int cell = cellOfRank[v];
        if (cell < 0) {
            coorsOut[3 * v + 0] = -1.0f;
            coorsOut[3 * v + 1] = -1.0f;
            coorsOut[3 * v + 2] = -1.0f;
        } else {
            coorsOut[3 * v + 0] = 0.0f;  // cz (GZ==1)
            coorsOut[3 * v + 1] = (float)(cell / GX);
            coorsOut[3 * v + 2] = (float)(cell % GX);
        }
    }
}

extern "C" void kernel_launch(void* const* d_in, const int* in_sizes, int n_in,
                              void* d_out, int out_size, void* d_ws, size_t ws_size,
                              hipStream_t stream) {
    const float4* pts = (const float4*)d_in[0];
    int n = in_sizes[0] / 4;  // 2,000,000
    int W = (n + 63) >> 6;    // 31250 bitmap words
    int K = PREFIX_K < n ? PREFIX_K : n;

    char* ws = (char*)d_ws;
    size_t off = 0;
    auto alloc = [&](size_t bytes) -> void* {
        void* p = (void*)(ws + off);
        off = (off + bytes + 255) & ~(size_t)255;
        return p;
    };
    int* first = (int*)alloc((size_t)(G_TOTAL + 8) * 4);  // + dcount + ticket
    int* dcount = first + G_TOTAL;
    int* ticket = first + G_TOTAL + 1;
    int* lin = (int*)alloc((size_t)n * 4);
    u64* bits = (u64*)alloc((size_t)W * 8);
    unsigned* wordLocal = (unsigned*)alloc((size_t)W * 4);
    int* sums = (int*)alloc(128 * 4);
    int* rank = (int*)alloc((size_t)G_TOTAL * 4);
    int* vcount = (int*)alloc((size_t)MAX_VOX * 4);
    int* cellOfRank = (int*)alloc((size_t)MAX_VOX * 4);
    int* list = (int*)alloc((size_t)MAX_VOX * CAP * 4);
    (void)ws_size;
    (void)n_in;
    (void)out_size;

    float* out = (float*)d_out;
    float4* voxOut = (float4*)out;                          // 20000*32*4
    float* coorsOut = out + (size_t)MAX_VOX * MAX_PTS * 4;  // 20000*3
    float* npOut = coorsOut + (size_t)MAX_VOX * 3;          // 20000
    float* nvOut = npOut + MAX_VOX;                         // 1

    // first/dcount/ticket all -> 0x7F7F7F7F (dcount re-zeroed in claimK)
    hipMemsetAsync(first, 0x7F, (size_t)(G_TOTAL + 8) * 4, stream);

    int nbK = (K + 255) / 256;        // 256
    int nbP = (n + 255) / 256;        // 7813
    int nbC = (G_TOTAL + 255) / 256;  // 837
    int nbW = (W + 255) / 256;        // 123

    claimK<<<nbK, 256, 0, stream>>>(pts, first, dcount, K);
    linAll<<<nbP, 256, 0, stream>>>(pts, lin, bits, vcount, cellOfRank, rank,
                                    W, n);
    countD<<<nbC, 256, 0, stream>>>(first, dcount);
    guard<<<256, 256, 0, stream>>>(pts, first, dcount, K, n);
    markFirst<<<nbC, 256, 0, stream>>>(first, bits, n);
    kScan<<<nbW, 256, 0, stream>>>(bits, wordLocal, sums, ticket, nvOut, W, nbW);
    rankCells<<<nbC, 256, 0, stream>>>(first, bits, wordLocal, sums, rank,
                                       cellOfRank, n);
    pass5<<<nbP, 256, 0, stream>>>(lin, rank, vcount, list, n);
    passF<<<MAX_VOX / 4, 256, 0, stream>>>(pts, vcount, cellOfRank, list,
                                           voxOut, coorsOut, npOut);
}